// Round 5
// baseline (113.898 us; speedup 1.0000x reference)
//
#include <hip/hip_runtime.h>
#include <math.h>
#include <stdint.h>

#define BB 16
#define DD 96
#define TT 512
#define HH 1024
#define NROW (BB*DD)
#define KT2 (HH/32)   // 32 k-tiles of 32 for gemm2

typedef __attribute__((ext_vector_type(4))) float floatx4;
typedef __attribute__((ext_vector_type(8))) short short8;

// ---------------- ws layout (bytes) ----------------
// x fp32 (3MB) | hfrag bf16 (3MB) | w1bf (1MB) | w2bf (1MB) | ps (48KB) | ps2 (48KB) | s (6KB)
#define WSOFF_X     0u
#define WSOFF_HFRAG 3145728u
#define WSOFF_W1BF  6291456u
#define WSOFF_W2BF  7340032u
#define WSOFF_PS    8388608u
#define WSOFF_PS2   8437760u
#define WSOFF_S     8486912u

__device__ __forceinline__ uint16_t f2bf(float v) {
    uint32_t u = __float_as_uint(v);
    uint32_t r = 0x7fffu + ((u >> 16) & 1u);
    return (uint16_t)((u + r) >> 16);
}

// K1: blocks 0..95: rowsums (16 rows each, 4 independent chains per wave).
//     blocks 96..511: weight swizzle.
__global__ __launch_bounds__(256) void k_pre(const float* __restrict__ residual,
                                             const float* __restrict__ W1,
                                             const float* __restrict__ W2,
                                             float* __restrict__ s,
                                             uint16_t* __restrict__ w1bf,
                                             uint16_t* __restrict__ w2bf) {
    const int bid = blockIdx.x;
    const int tid = threadIdx.x;
    const int wave = tid >> 6;
    const int lane = tid & 63;
    const int q = lane >> 4, l15 = lane & 15;

    if (bid < 96) {
        int row0 = bid*16 + wave*4;
        float acc[4] = {0.f, 0.f, 0.f, 0.f};
        #pragma unroll
        for (int cc = 0; cc < 4; ++cc) {
            const float* p = residual + (size_t)(row0 + cc)*TT;
            #pragma unroll
            for (int u = 0; u < TT/64; ++u) acc[cc] += p[lane + u*64];
        }
        #pragma unroll
        for (int o = 32; o > 0; o >>= 1) {
            #pragma unroll
            for (int cc = 0; cc < 4; ++cc) acc[cc] += __shfl_down(acc[cc], o, 64);
        }
        if (lane == 0) {
            #pragma unroll
            for (int cc = 0; cc < 4; ++cc) s[row0 + cc] = acc[cc];
        }
    } else {
        int wgid = (bid - 96)*4 + wave;
        const int nw = (512 - 96)*4;
        for (int u = wgid; u < 2048; u += nw) {
            const float* W; uint16_t* ob; int KT, N, b;
            if (u < 1024) { W = W1; ob = w1bf; KT = 16; N = 1024; b = u; }
            else          { W = W2; ob = w2bf; KT = 32; N = 512;  b = u - 1024; }
            int tile_n = b / KT, tile_k = b % KT;
            const float* src = W + (size_t)(tile_k*32 + q*8)*N + tile_n*16 + l15;
            uint16_t tmp[8];
            #pragma unroll
            for (int j = 0; j < 8; ++j) tmp[j] = f2bf(src[(size_t)j*N]);
            uint16_t* dst = ob + ((size_t)b*64 + lane)*8;
            *reinterpret_cast<ushort4*>(dst)     = *reinterpret_cast<ushort4*>(&tmp[0]);
            *reinterpret_cast<ushort4*>(dst + 4) = *reinterpret_cast<ushort4*>(&tmp[4]);
        }
    }
}

// K2: softmax rows computed in-LDS from s, then x = A@r + r, with BN partial sums.
__global__ __launch_bounds__(256) void k_attn(const float* __restrict__ residual,
                                              const float* __restrict__ s,
                                              float* __restrict__ x,
                                              float* __restrict__ ps,
                                              float* __restrict__ ps2) {
    __shared__ float rlds[DD*64];      // 24KB
    __shared__ float slds[DD];         // raw rowsums for this batch
    __shared__ float aLDS[24*DD];      // 24 softmax rows (this block's ig-slice), 9KB
    const int u = blockIdx.x;           // 512 = 16 b * 8 chunk * 4 ig
    const int b = u >> 5, chunk = (u >> 2) & 7, ig = u & 3;
    const int tid = threadIdx.x;
    const int wave = tid >> 6;
    const int lane = tid & 63;

    const float4* rb4 = reinterpret_cast<const float4*>(residual + (size_t)b*DD*TT);
    float4* rl4 = reinterpret_cast<float4*>(rlds);
    #pragma unroll
    for (int sx = 0; sx < 6; ++sx) {
        int idx = tid + sx*256;
        int i = idx >> 4, t4 = idx & 15;
        rl4[idx] = rb4[(size_t)i*(TT/4) + chunk*16 + t4];
    }
    if (tid < DD) slds[tid] = s[b*DD + tid];
    __syncthreads();

    // each wave computes softmax for its 6 rows (global rows ig*24 + wave*6 + rr)
    const float c = 1.0f / (512.0f * 22.627416997969522f);  // T^-1.5
    float sj_lo = slds[lane];
    float sj_hi = (lane < 32) ? slds[64 + lane] : 0.f;
    #pragma unroll
    for (int rr = 0; rr < 6; ++rr) {
        int iloc = wave*6 + rr;
        float si = slds[ig*24 + iloc] * c;
        float v1 = si * sj_lo;
        float v2 = (lane < 32) ? si * sj_hi : -1e30f;
        float m = fmaxf(v1, v2);
        #pragma unroll
        for (int o = 1; o < 64; o <<= 1) m = fmaxf(m, __shfl_xor(m, o, 64));
        float p1 = __expf(v1 - m);
        float p2 = (lane < 32) ? __expf(v2 - m) : 0.f;
        float sum = p1 + p2;
        #pragma unroll
        for (int o = 1; o < 64; o <<= 1) sum += __shfl_xor(sum, o, 64);
        float inv = 1.0f / sum;
        aLDS[iloc*DD + lane] = p1 * inv;
        if (lane < 32) aLDS[iloc*DD + 64 + lane] = p2 * inv;
    }
    // aLDS rows are wave-local (written and read by the same wave) -> no barrier needed

    int i0 = ig*24 + wave*6;
    float acc[6];
    #pragma unroll
    for (int rr = 0; rr < 6; ++rr) acc[rr] = rlds[(i0+rr)*64 + lane];
    #pragma unroll 4
    for (int j4 = 0; j4 < DD/4; ++j4) {
        float4 a[6];
        #pragma unroll
        for (int rr = 0; rr < 6; ++rr)
            a[rr] = *reinterpret_cast<const float4*>(&aLDS[(wave*6+rr)*DD + j4*4]);
        float rv[4];
        #pragma unroll
        for (int uu = 0; uu < 4; ++uu) rv[uu] = rlds[(j4*4+uu)*64 + lane];
        #pragma unroll
        for (int rr = 0; rr < 6; ++rr) {
            acc[rr] = fmaf(a[rr].x, rv[0], acc[rr]);
            acc[rr] = fmaf(a[rr].y, rv[1], acc[rr]);
            acc[rr] = fmaf(a[rr].z, rv[2], acc[rr]);
            acc[rr] = fmaf(a[rr].w, rv[3], acc[rr]);
        }
    }
    #pragma unroll
    for (int rr = 0; rr < 6; ++rr) {
        float v = acc[rr];
        x[((size_t)b*DD + i0 + rr)*TT + chunk*64 + lane] = v;
        float s1 = v, s2 = v*v;
        #pragma unroll
        for (int o = 32; o > 0; o >>= 1) {
            s1 += __shfl_down(s1, o, 64);
            s2 += __shfl_down(s2, o, 64);
        }
        if (lane == 0) {
            int d = i0 + rr;
            ps [d*128 + b*8 + chunk] = s1;
            ps2[d*128 + b*8 + chunk] = s2;
        }
    }
}

// Inline BN finalize for the 32 channels of one M=32 block. scs[32][2] in LDS.
// 32 groups x 8 threads; group dg handles channel d = m0%DD + dg.
__device__ __forceinline__ void bn_finalize32(const float* __restrict__ ps,
                                              const float* __restrict__ ps2,
                                              const float* __restrict__ bng,
                                              const float* __restrict__ bnb,
                                              int m0, int tid, float* scs) {
    int dg = tid >> 3, uu = tid & 7;
    int d = (m0 % DD) + dg;
    const float4* p1 = reinterpret_cast<const float4*>(ps  + d*128 + uu*16);
    const float4* p2 = reinterpret_cast<const float4*>(ps2 + d*128 + uu*16);
    float s1 = 0.f, s2 = 0.f;
    #pragma unroll
    for (int j = 0; j < 4; ++j) {
        float4 a = p1[j]; s1 += a.x+a.y+a.z+a.w;
        float4 b = p2[j]; s2 += b.x+b.y+b.z+b.w;
    }
    #pragma unroll
    for (int o = 1; o < 8; o <<= 1) {
        s1 += __shfl_xor(s1, o, 8);
        s2 += __shfl_xor(s2, o, 8);
    }
    if (uu == 0) {
        const float invn = 1.0f / (float)(BB*TT);
        float mu  = s1 * invn;
        float var = s2 * invn - mu*mu;
        float rs  = rsqrtf(var + 1e-5f);
        float scv = rs * bng[d];
        scs[dg*2]     = scv;
        scs[dg*2 + 1] = bnb[d] - mu*scv;
    }
}

// K3: gemm1 with inline BN, M=32 per block (halves w1bf L2 traffic).
// grid (48, 8) x 256.  M=32, N=128 per block.
__global__ __launch_bounds__(256) void k_gemm1(const float* __restrict__ x,
                                               const float* __restrict__ ps,
                                               const float* __restrict__ ps2,
                                               const float* __restrict__ bng,
                                               const float* __restrict__ bnb,
                                               const uint16_t* __restrict__ w1bf,
                                               const float* __restrict__ b1,
                                               uint16_t* __restrict__ hfrag) {
    __shared__ __align__(16) uint16_t fragA[2][16*64*8];   // 32KB
    __shared__ __align__(16) uint16_t cs[32][136];         // 8.5KB
    __shared__ float scs[64];
    const int mt0 = blockIdx.x*2;
    const int m0 = mt0*16;
    const int tid = threadIdx.x;
    const int wave = tid >> 6;
    const int lane = tid & 63;
    const int q = lane >> 4, l15 = lane & 15;

    bn_finalize32(ps, ps2, bng, bnb, m0, tid, scs);
    __syncthreads();

    // build bf16 A-fragments (BN applied inline): 2048 slots, 8 per thread
    #pragma unroll
    for (int r4 = 0; r4 < 8; ++r4) {
        int pi = tid + r4*256;
        int mi = pi >> 10;
        int rem = pi & 1023;
        int kk = rem >> 6, pl = rem & 63;
        int pq = pl >> 4, pr = pl & 15;
        int rloc = mi*16 + pr;
        float scv = scs[rloc*2], shv = scs[rloc*2 + 1];
        const float* xp = x + (size_t)(m0 + rloc)*TT + kk*32 + pq*8;
        float4 v0 = *reinterpret_cast<const float4*>(xp);
        float4 v1 = *reinterpret_cast<const float4*>(xp + 4);
        ushort4 o0, o1;
        o0.x = f2bf(v0.x*scv + shv); o0.y = f2bf(v0.y*scv + shv);
        o0.z = f2bf(v0.z*scv + shv); o0.w = f2bf(v0.w*scv + shv);
        o1.x = f2bf(v1.x*scv + shv); o1.y = f2bf(v1.y*scv + shv);
        o1.z = f2bf(v1.z*scv + shv); o1.w = f2bf(v1.w*scv + shv);
        uint16_t* fp = fragA[mi] + ((size_t)kk*64 + pl)*8;
        *reinterpret_cast<ushort4*>(fp)     = o0;
        *reinterpret_cast<ushort4*>(fp + 4) = o1;
    }
    __syncthreads();

    const int n0 = blockIdx.y*128 + wave*32;
    floatx4 acc4[2][2] = {};
    const uint16_t* b0p = w1bf + ((size_t)((n0>>4)    )*16*64 + lane)*8;
    const uint16_t* b1p = w1bf + ((size_t)((n0>>4) + 1)*16*64 + lane)*8;
    #pragma unroll
    for (int kk = 0; kk < 16; ++kk) {
        short8 bb0 = *reinterpret_cast<const short8*>(b0p + kk*512);
        short8 bb1 = *reinterpret_cast<const short8*>(b1p + kk*512);
        short8 a0  = *reinterpret_cast<const short8*>(fragA[0] + (kk*64 + lane)*8);
        short8 a1  = *reinterpret_cast<const short8*>(fragA[1] + (kk*64 + lane)*8);
        acc4[0][0] = __builtin_amdgcn_mfma_f32_16x16x32_bf16(a0, bb0, acc4[0][0], 0, 0, 0);
        acc4[0][1] = __builtin_amdgcn_mfma_f32_16x16x32_bf16(a0, bb1, acc4[0][1], 0, 0, 0);
        acc4[1][0] = __builtin_amdgcn_mfma_f32_16x16x32_bf16(a1, bb0, acc4[1][0], 0, 0, 0);
        acc4[1][1] = __builtin_amdgcn_mfma_f32_16x16x32_bf16(a1, bb1, acc4[1][1], 0, 0, 0);
    }
    #pragma unroll
    for (int mi = 0; mi < 2; ++mi) {
        #pragma unroll
        for (int nf = 0; nf < 2; ++nf) {
            int coll = wave*32 + nf*16 + l15;
            float bias = b1[blockIdx.y*128 + coll];
            #pragma unroll
            for (int r = 0; r < 4; ++r) {
                float v = acc4[mi][nf][r] + bias;
                float gl = 0.5f * v * (1.0f + erff(v * 0.7071067811865475f));
                cs[mi*16 + q*4 + r][coll] = f2bf(gl);
            }
        }
    }
    __syncthreads();
    // 8 chunk-writes (2 mtiles x 4 k-chunks), 2 per wave
    #pragma unroll
    for (int cc = 0; cc < 2; ++cc) {
        int idx = wave*2 + cc;           // 0..7
        int mi = idx >> 2, c = idx & 3;
        const uint4* srcp = reinterpret_cast<const uint4*>(&cs[mi*16 + l15][c*32 + q*8]);
        size_t chunk = (size_t)(mt0 + mi)*KT2 + (blockIdx.y*4 + c);
        reinterpret_cast<uint4*>(hfrag)[chunk*64 + lane] = *srcp;
    }
}

// K4: gemm2 + bias + BN(x) residual (fp32), M=32 per block (halves w2bf L2 traffic).
// grid (48, 4) x 256.
__global__ __launch_bounds__(256) void k_gemm2(const uint16_t* __restrict__ hfrag,
                                               const uint16_t* __restrict__ w2bf,
                                               const float* __restrict__ b2,
                                               const float* __restrict__ x,
                                               const float* __restrict__ ps,
                                               const float* __restrict__ ps2,
                                               const float* __restrict__ bng,
                                               const float* __restrict__ bnb,
                                               float* __restrict__ y) {
    __shared__ float scs[64];
    const int mt0 = blockIdx.x*2;
    const int m0 = mt0*16;
    const int tid = threadIdx.x;
    const int wave = tid >> 6;
    const int lane = tid & 63;
    const int q = lane >> 4, l15 = lane & 15;
    const int n0 = blockIdx.y*128 + wave*32;

    bn_finalize32(ps, ps2, bng, bnb, m0, tid, scs);
    __syncthreads();

    floatx4 acc[2][2] = {};
    const uint16_t* a0p = hfrag + ((size_t)mt0*KT2*64 + lane)*8;
    const uint16_t* a1p = hfrag + ((size_t)(mt0 + 1)*KT2*64 + lane)*8;
    const uint16_t* b0p = w2bf + ((size_t)((n0>>4)    )*32*64 + lane)*8;
    const uint16_t* b1p = w2bf + ((size_t)((n0>>4) + 1)*32*64 + lane)*8;
    #pragma unroll
    for (int kk = 0; kk < 32; ++kk) {
        short8 bb0 = *reinterpret_cast<const short8*>(b0p + kk*512);
        short8 bb1 = *reinterpret_cast<const short8*>(b1p + kk*512);
        short8 a0  = *reinterpret_cast<const short8*>(a0p + kk*512);
        short8 a1  = *reinterpret_cast<const short8*>(a1p + kk*512);
        acc[0][0] = __builtin_amdgcn_mfma_f32_16x16x32_bf16(a0, bb0, acc[0][0], 0, 0, 0);
        acc[0][1] = __builtin_amdgcn_mfma_f32_16x16x32_bf16(a0, bb1, acc[0][1], 0, 0, 0);
        acc[1][0] = __builtin_amdgcn_mfma_f32_16x16x32_bf16(a1, bb0, acc[1][0], 0, 0, 0);
        acc[1][1] = __builtin_amdgcn_mfma_f32_16x16x32_bf16(a1, bb1, acc[1][1], 0, 0, 0);
    }
    #pragma unroll
    for (int mi = 0; mi < 2; ++mi) {
        #pragma unroll
        for (int nf = 0; nf < 2; ++nf) {
            int col = n0 + nf*16 + l15;
            float bias = b2[col];
            #pragma unroll
            for (int r = 0; r < 4; ++r) {
                int rloc = mi*16 + q*4 + r;
                int row = m0 + rloc;
                float xb = x[(size_t)row*TT + col]*scs[rloc*2] + scs[rloc*2 + 1];
                y[(size_t)row*TT + col] = acc[mi][nf][r] + bias + xb;
            }
        }
    }
}

// K5: LayerNorm, 4 rows per block (1 row per wave). grid 384 x 256.
__global__ __launch_bounds__(256) void k_ln(float* __restrict__ y,
                                            const float* __restrict__ lng,
                                            const float* __restrict__ lnb) {
    int wave = threadIdx.x >> 6;
    int lane = threadIdx.x & 63;
    int row = blockIdx.x*4 + wave;
    float4* p = reinterpret_cast<float4*>(y + (size_t)row*TT);
    float4 v0 = p[lane*2], v1 = p[lane*2 + 1];
    float s  = v0.x+v0.y+v0.z+v0.w + v1.x+v1.y+v1.z+v1.w;
    float s2 = v0.x*v0.x+v0.y*v0.y+v0.z*v0.z+v0.w*v0.w
             + v1.x*v1.x+v1.y*v1.y+v1.z*v1.z+v1.w*v1.w;
    #pragma unroll
    for (int o = 1; o < 64; o <<= 1) {
        s  += __shfl_xor(s,  o, 64);
        s2 += __shfl_xor(s2, o, 64);
    }
    float mu = s * (1.0f/TT);
    float var = s2 * (1.0f/TT) - mu*mu;
    float rs = rsqrtf(var + 1e-5f);
    const float4* g4 = reinterpret_cast<const float4*>(lng);
    const float4* b4 = reinterpret_cast<const float4*>(lnb);
    float4 g0 = g4[lane*2], g1 = g4[lane*2+1];
    float4 bb0 = b4[lane*2], bb1 = b4[lane*2+1];
    float4 o0, o1;
    o0.x = (v0.x-mu)*rs*g0.x + bb0.x;  o0.y = (v0.y-mu)*rs*g0.y + bb0.y;
    o0.z = (v0.z-mu)*rs*g0.z + bb0.z;  o0.w = (v0.w-mu)*rs*g0.w + bb0.w;
    o1.x = (v1.x-mu)*rs*g1.x + bb1.x;  o1.y = (v1.y-mu)*rs*g1.y + bb1.y;
    o1.z = (v1.z-mu)*rs*g1.z + bb1.z;  o1.w = (v1.w-mu)*rs*g1.w + bb1.w;
    p[lane*2] = o0;  p[lane*2+1] = o1;
}

extern "C" void kernel_launch(void* const* d_in, const int* in_sizes, int n_in,
                              void* d_out, int out_size, void* d_ws, size_t ws_size,
                              hipStream_t stream) {
    (void)in_sizes; (void)n_in; (void)out_size; (void)ws_size;
    const float* residual = (const float*)d_in[0];
    const float* bng = (const float*)d_in[1];
    const float* bnb = (const float*)d_in[2];
    const float* lng = (const float*)d_in[3];
    const float* lnb = (const float*)d_in[4];
    const float* W1  = (const float*)d_in[5];
    const float* b1  = (const float*)d_in[6];
    const float* W2  = (const float*)d_in[7];
    const float* b2  = (const float*)d_in[8];
    float* out = (float*)d_out;
    char* ws = (char*)d_ws;
    float*    x     = (float*)(ws + WSOFF_X);
    uint16_t* hfrag = (uint16_t*)(ws + WSOFF_HFRAG);
    uint16_t* w1bf  = (uint16_t*)(ws + WSOFF_W1BF);
    uint16_t* w2bf  = (uint16_t*)(ws + WSOFF_W2BF);
    float*    ps    = (float*)(ws + WSOFF_PS);
    float*    ps2   = (float*)(ws + WSOFF_PS2);
    float*    s     = (float*)(ws + WSOFF_S);

    k_pre  <<<512, 256, 0, stream>>>(residual, W1, W2, s, w1bf, w2bf);
    k_attn <<<512, 256, 0, stream>>>(residual, s, x, ps, ps2);
    k_gemm1<<<dim3(48, 8), 256, 0, stream>>>(x, ps, ps2, bng, bnb, w1bf, b1, hfrag);
    k_gemm2<<<dim3(48, 4), 256, 0, stream>>>(hfrag, w2bf, b2, x, ps, ps2, bng, bnb, out);
    k_ln   <<<384, 256, 0, stream>>>(out, lng, lnb);
}

// Round 6
// 111.113 us; speedup vs baseline: 1.0251x; 1.0251x over previous
//
#include <hip/hip_runtime.h>
#include <math.h>
#include <stdint.h>

#define BB 16
#define DD 96
#define TT 512
#define HH 1024
#define NROW (BB*DD)
#define KT2 (HH/32)   // 32 k-tiles of 32 for gemm2

typedef __attribute__((ext_vector_type(4))) float floatx4;
typedef __attribute__((ext_vector_type(8))) short short8;

// ---------------- ws layout (bytes) ----------------
// x fp32 (3MB) | hfrag bf16 (3MB) | w1bf (1MB) | w2bf (1MB) | ps (48KB) | ps2 (48KB) | s (6KB)
#define WSOFF_X     0u
#define WSOFF_HFRAG 3145728u
#define WSOFF_W1BF  6291456u
#define WSOFF_W2BF  7340032u
#define WSOFF_PS    8388608u
#define WSOFF_PS2   8437760u
#define WSOFF_S     8486912u

__device__ __forceinline__ uint16_t f2bf(float v) {
    uint32_t u = __float_as_uint(v);
    uint32_t r = 0x7fffu + ((u >> 16) & 1u);
    return (uint16_t)((u + r) >> 16);
}

// K1: blocks 0..95: rowsums (16 rows each, 4 independent chains per wave).
//     blocks 96..511: weight swizzle.
__global__ __launch_bounds__(256) void k_pre(const float* __restrict__ residual,
                                             const float* __restrict__ W1,
                                             const float* __restrict__ W2,
                                             float* __restrict__ s,
                                             uint16_t* __restrict__ w1bf,
                                             uint16_t* __restrict__ w2bf) {
    const int bid = blockIdx.x;
    const int tid = threadIdx.x;
    const int wave = tid >> 6;
    const int lane = tid & 63;
    const int q = lane >> 4, l15 = lane & 15;

    if (bid < 96) {
        int row0 = bid*16 + wave*4;
        float acc[4] = {0.f, 0.f, 0.f, 0.f};
        #pragma unroll
        for (int cc = 0; cc < 4; ++cc) {
            const float* p = residual + (size_t)(row0 + cc)*TT;
            #pragma unroll
            for (int u = 0; u < TT/64; ++u) acc[cc] += p[lane + u*64];
        }
        #pragma unroll
        for (int o = 32; o > 0; o >>= 1) {
            #pragma unroll
            for (int cc = 0; cc < 4; ++cc) acc[cc] += __shfl_down(acc[cc], o, 64);
        }
        if (lane == 0) {
            #pragma unroll
            for (int cc = 0; cc < 4; ++cc) s[row0 + cc] = acc[cc];
        }
    } else {
        int wgid = (bid - 96)*4 + wave;
        const int nw = (512 - 96)*4;
        for (int u = wgid; u < 2048; u += nw) {
            const float* W; uint16_t* ob; int KT, N, b;
            if (u < 1024) { W = W1; ob = w1bf; KT = 16; N = 1024; b = u; }
            else          { W = W2; ob = w2bf; KT = 32; N = 512;  b = u - 1024; }
            int tile_n = b / KT, tile_k = b % KT;
            const float* src = W + (size_t)(tile_k*32 + q*8)*N + tile_n*16 + l15;
            uint16_t tmp[8];
            #pragma unroll
            for (int j = 0; j < 8; ++j) tmp[j] = f2bf(src[(size_t)j*N]);
            uint16_t* dst = ob + ((size_t)b*64 + lane)*8;
            *reinterpret_cast<ushort4*>(dst)     = *reinterpret_cast<ushort4*>(&tmp[0]);
            *reinterpret_cast<ushort4*>(dst + 4) = *reinterpret_cast<ushort4*>(&tmp[4]);
        }
    }
}

// K2: softmax rows computed in-LDS from s, then x = A@r + r, with BN partial sums.
__global__ __launch_bounds__(256) void k_attn(const float* __restrict__ residual,
                                              const float* __restrict__ s,
                                              float* __restrict__ x,
                                              float* __restrict__ ps,
                                              float* __restrict__ ps2) {
    __shared__ float rlds[DD*64];      // 24KB
    __shared__ float slds[DD];         // raw rowsums for this batch
    __shared__ float aLDS[24*DD];      // 24 softmax rows (this block's ig-slice), 9KB
    const int u = blockIdx.x;           // 512 = 16 b * 8 chunk * 4 ig
    const int b = u >> 5, chunk = (u >> 2) & 7, ig = u & 3;
    const int tid = threadIdx.x;
    const int wave = tid >> 6;
    const int lane = tid & 63;

    const float4* rb4 = reinterpret_cast<const float4*>(residual + (size_t)b*DD*TT);
    float4* rl4 = reinterpret_cast<float4*>(rlds);
    #pragma unroll
    for (int sx = 0; sx < 6; ++sx) {
        int idx = tid + sx*256;
        int i = idx >> 4, t4 = idx & 15;
        rl4[idx] = rb4[(size_t)i*(TT/4) + chunk*16 + t4];
    }
    if (tid < DD) slds[tid] = s[b*DD + tid];
    __syncthreads();

    // each wave computes softmax for its 6 rows (global rows ig*24 + wave*6 + rr)
    const float c = 1.0f / (512.0f * 22.627416997969522f);  // T^-1.5
    float sj_lo = slds[lane];
    float sj_hi = (lane < 32) ? slds[64 + lane] : 0.f;
    #pragma unroll
    for (int rr = 0; rr < 6; ++rr) {
        int iloc = wave*6 + rr;
        float si = slds[ig*24 + iloc] * c;
        float v1 = si * sj_lo;
        float v2 = (lane < 32) ? si * sj_hi : -1e30f;
        float m = fmaxf(v1, v2);
        #pragma unroll
        for (int o = 1; o < 64; o <<= 1) m = fmaxf(m, __shfl_xor(m, o, 64));
        float p1 = __expf(v1 - m);
        float p2 = (lane < 32) ? __expf(v2 - m) : 0.f;
        float sum = p1 + p2;
        #pragma unroll
        for (int o = 1; o < 64; o <<= 1) sum += __shfl_xor(sum, o, 64);
        float inv = 1.0f / sum;
        aLDS[iloc*DD + lane] = p1 * inv;
        if (lane < 32) aLDS[iloc*DD + 64 + lane] = p2 * inv;
    }
    // aLDS rows are wave-local (written and read by the same wave) -> no barrier needed

    int i0 = ig*24 + wave*6;
    float acc[6];
    #pragma unroll
    for (int rr = 0; rr < 6; ++rr) acc[rr] = rlds[(i0+rr)*64 + lane];
    #pragma unroll 4
    for (int j4 = 0; j4 < DD/4; ++j4) {
        float4 a[6];
        #pragma unroll
        for (int rr = 0; rr < 6; ++rr)
            a[rr] = *reinterpret_cast<const float4*>(&aLDS[(wave*6+rr)*DD + j4*4]);
        float rv[4];
        #pragma unroll
        for (int uu = 0; uu < 4; ++uu) rv[uu] = rlds[(j4*4+uu)*64 + lane];
        #pragma unroll
        for (int rr = 0; rr < 6; ++rr) {
            acc[rr] = fmaf(a[rr].x, rv[0], acc[rr]);
            acc[rr] = fmaf(a[rr].y, rv[1], acc[rr]);
            acc[rr] = fmaf(a[rr].z, rv[2], acc[rr]);
            acc[rr] = fmaf(a[rr].w, rv[3], acc[rr]);
        }
    }
    #pragma unroll
    for (int rr = 0; rr < 6; ++rr) {
        float v = acc[rr];
        x[((size_t)b*DD + i0 + rr)*TT + chunk*64 + lane] = v;
        float s1 = v, s2 = v*v;
        #pragma unroll
        for (int o = 32; o > 0; o >>= 1) {
            s1 += __shfl_down(s1, o, 64);
            s2 += __shfl_down(s2, o, 64);
        }
        if (lane == 0) {
            int d = i0 + rr;
            ps [d*128 + b*8 + chunk] = s1;
            ps2[d*128 + b*8 + chunk] = s2;
        }
    }
}

// Inline BN finalize for the 16 channels of one mtile. scs[16][2] in LDS.
// Thread group dg = tid>>4 (16 threads each) handles channel d=(m0+dg)%DD.
__device__ __forceinline__ void bn_finalize16(const float* __restrict__ ps,
                                              const float* __restrict__ ps2,
                                              const float* __restrict__ bng,
                                              const float* __restrict__ bnb,
                                              int m0, int tid, float* scs) {
    if (tid < 256) {
        int dg = tid >> 4, uu = tid & 15;
        int d = (m0 + dg) % DD;
        const float4* p1 = reinterpret_cast<const float4*>(ps  + d*128 + uu*8);
        const float4* p2 = reinterpret_cast<const float4*>(ps2 + d*128 + uu*8);
        float4 a0 = p1[0], a1 = p1[1];
        float4 b0 = p2[0], b1 = p2[1];
        float s1 = a0.x+a0.y+a0.z+a0.w + a1.x+a1.y+a1.z+a1.w;
        float s2 = b0.x+b0.y+b0.z+b0.w + b1.x+b1.y+b1.z+b1.w;
        #pragma unroll
        for (int o = 1; o < 16; o <<= 1) {
            s1 += __shfl_xor(s1, o, 16);
            s2 += __shfl_xor(s2, o, 16);
        }
        if (uu == 0) {
            const float invn = 1.0f / (float)(BB*TT);
            float mu  = s1 * invn;
            float var = s2 * invn - mu*mu;
            float rs  = rsqrtf(var + 1e-5f);
            float scv = rs * bng[d];
            scs[dg*2]     = scv;
            scs[dg*2 + 1] = bnb[d] - mu*scv;
        }
    }
}

// K3: gemm1 with inline BN. grid (96, 8) x 256.  M=16, N=128 per block.
__global__ __launch_bounds__(256) void k_gemm1(const float* __restrict__ x,
                                               const float* __restrict__ ps,
                                               const float* __restrict__ ps2,
                                               const float* __restrict__ bng,
                                               const float* __restrict__ bnb,
                                               const uint16_t* __restrict__ w1bf,
                                               const float* __restrict__ b1,
                                               uint16_t* __restrict__ hfrag) {
    __shared__ __align__(16) uint16_t fragA[16*64*8];   // 16KB
    __shared__ __align__(16) uint16_t cs[16][136];
    __shared__ float scs[32];
    const int mtile = blockIdx.x;
    const int m0 = mtile*16;
    const int tid = threadIdx.x;
    const int wave = tid >> 6;
    const int lane = tid & 63;
    const int q = lane >> 4, l15 = lane & 15;

    bn_finalize16(ps, ps2, bng, bnb, m0, tid, scs);
    __syncthreads();

    // build bf16 A-fragments (BN applied inline): 1024 slots, 4 per thread
    #pragma unroll
    for (int r4 = 0; r4 < 4; ++r4) {
        int pi = tid + r4*256;
        int kk = pi >> 6, pl = pi & 63;
        int pq = pl >> 4, pr = pl & 15;
        float scv = scs[pr*2], shv = scs[pr*2 + 1];
        const float* xp = x + (size_t)(m0 + pr)*TT + kk*32 + pq*8;
        float4 v0 = *reinterpret_cast<const float4*>(xp);
        float4 v1 = *reinterpret_cast<const float4*>(xp + 4);
        ushort4 o0, o1;
        o0.x = f2bf(v0.x*scv + shv); o0.y = f2bf(v0.y*scv + shv);
        o0.z = f2bf(v0.z*scv + shv); o0.w = f2bf(v0.w*scv + shv);
        o1.x = f2bf(v1.x*scv + shv); o1.y = f2bf(v1.y*scv + shv);
        o1.z = f2bf(v1.z*scv + shv); o1.w = f2bf(v1.w*scv + shv);
        uint16_t* fp = fragA + ((size_t)kk*64 + pl)*8;
        *reinterpret_cast<ushort4*>(fp)     = o0;
        *reinterpret_cast<ushort4*>(fp + 4) = o1;
    }
    __syncthreads();

    const int n0 = blockIdx.y*128 + wave*32;
    floatx4 acc4[2] = {};
    const uint16_t* b0p = w1bf + ((size_t)((n0>>4)    )*16*64 + lane)*8;
    const uint16_t* b1p = w1bf + ((size_t)((n0>>4) + 1)*16*64 + lane)*8;
    #pragma unroll
    for (int kk = 0; kk < 16; ++kk) {
        short8 a  = *reinterpret_cast<const short8*>(fragA + (kk*64 + lane)*8);
        short8 bb0 = *reinterpret_cast<const short8*>(b0p + kk*512);
        short8 bb1 = *reinterpret_cast<const short8*>(b1p + kk*512);
        acc4[0] = __builtin_amdgcn_mfma_f32_16x16x32_bf16(a, bb0, acc4[0], 0, 0, 0);
        acc4[1] = __builtin_amdgcn_mfma_f32_16x16x32_bf16(a, bb1, acc4[1], 0, 0, 0);
    }
    #pragma unroll
    for (int nf = 0; nf < 2; ++nf) {
        int coll = wave*32 + nf*16 + l15;
        float bias = b1[blockIdx.y*128 + coll];
        #pragma unroll
        for (int r = 0; r < 4; ++r) {
            float v = acc4[nf][r] + bias;
            float gl = 0.5f * v * (1.0f + erff(v * 0.7071067811865475f));
            cs[q*4 + r][coll] = f2bf(gl);
        }
    }
    __syncthreads();
    {
        int cchunk = wave;   // 4 waves -> 4 k-chunks of this block's 128-col slice
        const uint4* srcp = reinterpret_cast<const uint4*>(&cs[l15][cchunk*32 + q*8]);
        size_t chunk = (size_t)mtile*KT2 + (blockIdx.y*4 + cchunk);
        reinterpret_cast<uint4*>(hfrag)[chunk*64 + lane] = *srcp;
    }
}

// K4: gemm2 + bias + BN(x) residual (fp32) -> y (=out).  grid (96, 4) x 256.
// A-slice (32KB, shared by all 4 waves) staged in LDS once: removes 96KB/block
// of L1-thrashing redundant global A reads.
__global__ __launch_bounds__(256) void k_gemm2(const uint16_t* __restrict__ hfrag,
                                               const uint16_t* __restrict__ w2bf,
                                               const float* __restrict__ b2,
                                               const float* __restrict__ x,
                                               const float* __restrict__ ps,
                                               const float* __restrict__ ps2,
                                               const float* __restrict__ bng,
                                               const float* __restrict__ bnb,
                                               float* __restrict__ y) {
    __shared__ __align__(16) uint16_t aLDS[KT2*64*8];   // 32KB
    __shared__ float scs[32];
    const int mtile = blockIdx.x;
    const int m0 = mtile*16;
    const int tid = threadIdx.x;
    const int wave = tid >> 6;
    const int lane = tid & 63;
    const int q = lane >> 4, l15 = lane & 15;
    const int n0 = blockIdx.y*128 + wave*32;

    bn_finalize16(ps, ps2, bng, bnb, m0, tid, scs);
    // cooperative stage of this mtile's A fragments: 2048 uint4
    {
        const uint4* hsrc = reinterpret_cast<const uint4*>(hfrag + (size_t)mtile*KT2*64*8);
        uint4* adst = reinterpret_cast<uint4*>(aLDS);
        #pragma unroll
        for (int i = 0; i < 8; ++i) adst[tid + i*256] = hsrc[tid + i*256];
    }
    __syncthreads();

    floatx4 acc[2] = {};
    const uint16_t* b0p = w2bf + ((size_t)((n0>>4)    )*32*64 + lane)*8;
    const uint16_t* b1p = w2bf + ((size_t)((n0>>4) + 1)*32*64 + lane)*8;
    #pragma unroll
    for (int kk = 0; kk < 32; ++kk) {
        short8 a  = *reinterpret_cast<const short8*>(aLDS + (kk*64 + lane)*8);
        short8 bb0 = *reinterpret_cast<const short8*>(b0p + kk*512);
        short8 bb1 = *reinterpret_cast<const short8*>(b1p + kk*512);
        acc[0] = __builtin_amdgcn_mfma_f32_16x16x32_bf16(a, bb0, acc[0], 0, 0, 0);
        acc[1] = __builtin_amdgcn_mfma_f32_16x16x32_bf16(a, bb1, acc[1], 0, 0, 0);
    }
    #pragma unroll
    for (int nf = 0; nf < 2; ++nf) {
        int col = n0 + nf*16 + l15;
        float bias = b2[col];
        #pragma unroll
        for (int r = 0; r < 4; ++r) {
            int rloc = q*4 + r;
            int row = m0 + rloc;
            float xb = x[(size_t)row*TT + col]*scs[rloc*2] + scs[rloc*2 + 1];
            y[(size_t)row*TT + col] = acc[nf][r] + bias + xb;
        }
    }
}

// K5: LayerNorm, 4 rows per block (1 row per wave). grid 384 x 256.
__global__ __launch_bounds__(256) void k_ln(float* __restrict__ y,
                                            const float* __restrict__ lng,
                                            const float* __restrict__ lnb) {
    int wave = threadIdx.x >> 6;
    int lane = threadIdx.x & 63;
    int row = blockIdx.x*4 + wave;
    float4* p = reinterpret_cast<float4*>(y + (size_t)row*TT);
    float4 v0 = p[lane*2], v1 = p[lane*2 + 1];
    float s  = v0.x+v0.y+v0.z+v0.w + v1.x+v1.y+v1.z+v1.w;
    float s2 = v0.x*v0.x+v0.y*v0.y+v0.z*v0.z+v0.w*v0.w
             + v1.x*v1.x+v1.y*v1.y+v1.z*v1.z+v1.w*v1.w;
    #pragma unroll
    for (int o = 1; o < 64; o <<= 1) {
        s  += __shfl_xor(s,  o, 64);
        s2 += __shfl_xor(s2, o, 64);
    }
    float mu = s * (1.0f/TT);
    float var = s2 * (1.0f/TT) - mu*mu;
    float rs = rsqrtf(var + 1e-5f);
    const float4* g4 = reinterpret_cast<const float4*>(lng);
    const float4* b4 = reinterpret_cast<const float4*>(lnb);
    float4 g0 = g4[lane*2], g1 = g4[lane*2+1];
    float4 bb0 = b4[lane*2], bb1 = b4[lane*2+1];
    float4 o0, o1;
    o0.x = (v0.x-mu)*rs*g0.x + bb0.x;  o0.y = (v0.y-mu)*rs*g0.y + bb0.y;
    o0.z = (v0.z-mu)*rs*g0.z + bb0.z;  o0.w = (v0.w-mu)*rs*g0.w + bb0.w;
    o1.x = (v1.x-mu)*rs*g1.x + bb1.x;  o1.y = (v1.y-mu)*rs*g1.y + bb1.y;
    o1.z = (v1.z-mu)*rs*g1.z + bb1.z;  o1.w = (v1.w-mu)*rs*g1.w + bb1.w;
    p[lane*2] = o0;  p[lane*2+1] = o1;
}

extern "C" void kernel_launch(void* const* d_in, const int* in_sizes, int n_in,
                              void* d_out, int out_size, void* d_ws, size_t ws_size,
                              hipStream_t stream) {
    (void)in_sizes; (void)n_in; (void)out_size; (void)ws_size;
    const float* residual = (const float*)d_in[0];
    const float* bng = (const float*)d_in[1];
    const float* bnb = (const float*)d_in[2];
    const float* lng = (const float*)d_in[3];
    const float* lnb = (const float*)d_in[4];
    const float* W1  = (const float*)d_in[5];
    const float* b1  = (const float*)d_in[6];
    const float* W2  = (const float*)d_in[7];
    const float* b2  = (const float*)d_in[8];
    float* out = (float*)d_out;
    char* ws = (char*)d_ws;
    float*    x     = (float*)(ws + WSOFF_X);
    uint16_t* hfrag = (uint16_t*)(ws + WSOFF_HFRAG);
    uint16_t* w1bf  = (uint16_t*)(ws + WSOFF_W1BF);
    uint16_t* w2bf  = (uint16_t*)(ws + WSOFF_W2BF);
    float*    ps    = (float*)(ws + WSOFF_PS);
    float*    ps2   = (float*)(ws + WSOFF_PS2);
    float*    s     = (float*)(ws + WSOFF_S);

    k_pre  <<<512, 256, 0, stream>>>(residual, W1, W2, s, w1bf, w2bf);
    k_attn <<<512, 256, 0, stream>>>(residual, s, x, ps, ps2);
    k_gemm1<<<dim3(96, 8), 256, 0, stream>>>(x, ps, ps2, bng, bnb, w1bf, b1, hfrag);
    k_gemm2<<<dim3(96, 4), 256, 0, stream>>>(hfrag, w2bf, b2, x, ps, ps2, bng, bnb, out);
    k_ln   <<<384, 256, 0, stream>>>(out, lng, lnb);
}